// Round 14
// baseline (299.356 us; speedup 1.0000x reference)
//
#include <hip/hip_runtime.h>
#include <hip/hip_fp16.h>
#include <math.h>

#define NN 50000
#define NE 640000

typedef __bf16 bf16x8 __attribute__((ext_vector_type(8)));
typedef float f32x4 __attribute__((ext_vector_type(4)));

__device__ inline ushort f2bf_rne(float f) {
    uint u = __float_as_uint(f);
    uint r = u + 0x7FFFu + ((u >> 16) & 1u);
    return (ushort)(r >> 16);
}
__device__ inline float bf2f(ushort h) { return __uint_as_float(((uint)h) << 16); }

union BfU {
    ushort u[8];
    uint4 q;
    bf16x8 v;
};
union HU {
    uint4 q;
    __half h[8];
};

// ---------------- CSR build ----------------

__global__ void count_kernel(const int* __restrict__ dst, int* __restrict__ cnt, int E) {
    int e = blockIdx.x * blockDim.x + threadIdx.x;
    if (e < E) atomicAdd(&cnt[dst[e]], 1);
}

__global__ __launch_bounds__(256) void block_reduce_kernel(const int* __restrict__ cnt,
                                                           int* __restrict__ blk_sums, int N) {
    __shared__ int red[256];
    int tid = threadIdx.x;
    int base = blockIdx.x * 1024 + tid * 4;
    int s = 0;
    if (base + 3 < N) {
        int4 v = *reinterpret_cast<const int4*>(&cnt[base]);
        s = v.x + v.y + v.z + v.w;
    } else {
        for (int i = 0; i < 4; ++i)
            if (base + i < N) s += cnt[base + i];
    }
    red[tid] = s;
    __syncthreads();
    for (int off = 128; off > 0; off >>= 1) {
        if (tid < off) red[tid] += red[tid + off];
        __syncthreads();
    }
    if (tid == 0) blk_sums[blockIdx.x] = red[0];
}

__global__ __launch_bounds__(64) void scan_sums_kernel(int* __restrict__ blk_sums, int nblk) {
    int lane = threadIdx.x;
    int v = (lane < nblk) ? blk_sums[lane] : 0;
    for (int off = 1; off < 64; off <<= 1) {
        int u = __shfl_up(v, off);
        if (lane >= off) v += u;
    }
    int ex = __shfl_up(v, 1);
    if (lane == 0) ex = 0;
    if (lane < nblk) blk_sums[lane] = ex;
}

__global__ __launch_bounds__(256) void block_scan_kernel(const int* __restrict__ cnt,
                                                         const int* __restrict__ blk_offs,
                                                         int* __restrict__ row_ptr,
                                                         int* __restrict__ tmp_ptr,
                                                         float* __restrict__ dinv,
                                                         int N, int E) {
    __shared__ int warp_sums[4];
    int tid = threadIdx.x;
    int base = blockIdx.x * 1024 + tid * 4;
    int c[4];
    int s = 0;
#pragma unroll
    for (int i = 0; i < 4; ++i) {
        int idx = base + i;
        c[i] = (idx < N) ? cnt[idx] : 0;
        s += c[i];
    }
    int lane = tid & 63;
    int wv = tid >> 6;
    int v = s;
    for (int off = 1; off < 64; off <<= 1) {
        int u = __shfl_up(v, off);
        if (lane >= off) v += u;
    }
    if (lane == 63) warp_sums[wv] = v;
    __syncthreads();
    int woff = 0;
    for (int w = 0; w < wv; ++w) woff += warp_sums[w];
    int run = blk_offs[blockIdx.x] + woff + (v - s);
#pragma unroll
    for (int i = 0; i < 4; ++i) {
        int idx = base + i;
        if (idx < N) {
            row_ptr[idx] = run;
            tmp_ptr[idx] = run;
            run += c[i];
            dinv[idx] = rsqrtf((float)c[i] + 1.0f);
        }
    }
    if (blockIdx.x == 0 && tid == 0) row_ptr[N] = E;
}

__global__ void fill_kernel(const int* __restrict__ src, const int* __restrict__ dst,
                            int* __restrict__ tmp_ptr, int* __restrict__ col, int E) {
    int e = blockIdx.x * blockDim.x + threadIdx.x;
    if (e < E) {
        int d = dst[e];
        int pos = atomicAdd(&tmp_ptr[d], 1);
        col[pos] = src[e];
    }
}

// ---------------- split X: fp32 -> bf16 hi/lo planes (one-time, layer 1) ----------------

__global__ __launch_bounds__(256) void split_x_kernel(const float* __restrict__ X,
                                                      ushort* __restrict__ Xh,
                                                      ushort* __restrict__ Xl, int total8) {
    int i = blockIdx.x * 256 + threadIdx.x;
    if (i >= total8) return;
    const float* p = X + (size_t)i * 8;
    float4 a = *reinterpret_cast<const float4*>(p);
    float4 b = *reinterpret_cast<const float4*>(p + 4);
    float f[8] = {a.x, a.y, a.z, a.w, b.x, b.y, b.z, b.w};
    BfU H, L;
#pragma unroll
    for (int j = 0; j < 8; ++j) {
        ushort h = f2bf_rne(f[j]);
        H.u[j] = h;
        L.u[j] = f2bf_rne(f[j] - bf2f(h));
    }
    *reinterpret_cast<uint4*>(&Xh[(size_t)i * 8]) = H.q;
    *reinterpret_cast<uint4*>(&Xl[(size_t)i * 8]) = L.q;
}

// ---------------- GEMM via split-bf16 MFMA; A pre-split (NO in-loop conversion) ----------------
// G[r][c] = fp16( dinv[r] * sum_k X[r][k] * W[k][c] ), K = 128.
// X = Xh + Xl (bf16 planes); X*w ~= Xh*Wh + Xl*Wh + Xh*Wl (lo*lo dropped).
// 256 thr = 4 waves; 128 rows x 64 cols per block (blockIdx.y = col half).
// W converted once into LDS as MFMA-tiled bf16 hi/lo.
// mfma_f32_16x16x32_bf16; A-frag: row=lane&15, k0=(lane>>4)*8 (contiguous 16B);
// D layout: col = lane&15, row = (lane>>4)*4 + reg (m89-verified, refcheck'd R9).

template <int WSTRIDE>
__global__ __launch_bounds__(256, 3) void gemm_mfma_kernel(const ushort* __restrict__ Xh,
                                                           const ushort* __restrict__ Xl,
                                                           const float* __restrict__ W,
                                                           const float* __restrict__ dinv,
                                                           __half* __restrict__ G, int N) {
    __shared__ ushort lds_hi[16 * 512];
    __shared__ ushort lds_lo[16 * 512];
    const int tid = threadIdx.x;
    const int c0 = blockIdx.y * 64;

    for (int idx = tid; idx < 128 * 64; idx += 256) {
        int k = idx >> 6;
        int n = idx & 63;
        float w = W[k * WSTRIDE + c0 + n];
        ushort h = f2bf_rne(w);
        ushort l = f2bf_rne(w - bf2f(h));
        int kt = k >> 5;
        int t = n >> 4;
        int ln = (n & 15) | (((k >> 3) & 3) << 4);
        int pos = (kt * 4 + t) * 512 + ln * 8 + (k & 7);
        lds_hi[pos] = h;
        lds_lo[pos] = l;
    }
    __syncthreads();

    const int wave = tid >> 6;
    const int lane = tid & 63;
    const int lhi = lane >> 4;
    const int llo = lane & 15;
    const int r0 = blockIdx.x * 128 + wave * 32;

    int ar0 = min(r0 + llo, N - 1);
    int ar1 = min(r0 + 16 + llo, N - 1);
    const ushort* Xh0 = Xh + (size_t)ar0 * 128 + lhi * 8;
    const ushort* Xl0 = Xl + (size_t)ar0 * 128 + lhi * 8;
    const ushort* Xh1 = Xh + (size_t)ar1 * 128 + lhi * 8;
    const ushort* Xl1 = Xl + (size_t)ar1 * 128 + lhi * 8;

    f32x4 acc0[4], acc1[4];
#pragma unroll
    for (int t = 0; t < 4; ++t) {
        acc0[t] = (f32x4){0.f, 0.f, 0.f, 0.f};
        acc1[t] = (f32x4){0.f, 0.f, 0.f, 0.f};
    }

#pragma unroll
    for (int kt = 0; kt < 4; ++kt) {
        const ushort* hp = &lds_hi[kt * 4 * 512 + lane * 8];
        const ushort* lp = &lds_lo[kt * 4 * 512 + lane * 8];
        bf16x8 bh[4], bl[4];
#pragma unroll
        for (int t = 0; t < 4; ++t) {
            bh[t] = *reinterpret_cast<const bf16x8*>(hp + t * 512);
            bl[t] = *reinterpret_cast<const bf16x8*>(lp + t * 512);
        }
        bf16x8 ah0 = *reinterpret_cast<const bf16x8*>(Xh0 + kt * 32);
        bf16x8 al0 = *reinterpret_cast<const bf16x8*>(Xl0 + kt * 32);
        bf16x8 ah1 = *reinterpret_cast<const bf16x8*>(Xh1 + kt * 32);
        bf16x8 al1 = *reinterpret_cast<const bf16x8*>(Xl1 + kt * 32);
#pragma unroll
        for (int t = 0; t < 4; ++t) {
            acc0[t] = __builtin_amdgcn_mfma_f32_16x16x32_bf16(ah0, bh[t], acc0[t], 0, 0, 0);
            acc1[t] = __builtin_amdgcn_mfma_f32_16x16x32_bf16(ah1, bh[t], acc1[t], 0, 0, 0);
            acc0[t] = __builtin_amdgcn_mfma_f32_16x16x32_bf16(al0, bh[t], acc0[t], 0, 0, 0);
            acc1[t] = __builtin_amdgcn_mfma_f32_16x16x32_bf16(al1, bh[t], acc1[t], 0, 0, 0);
            acc0[t] = __builtin_amdgcn_mfma_f32_16x16x32_bf16(ah0, bl[t], acc0[t], 0, 0, 0);
            acc1[t] = __builtin_amdgcn_mfma_f32_16x16x32_bf16(ah1, bl[t], acc1[t], 0, 0, 0);
        }
    }

    const int rbase = r0 + lhi * 4;
#pragma unroll
    for (int i = 0; i < 4; ++i) {
        int row = rbase + i;
        if (row < N) {
            float dv = dinv[row];
#pragma unroll
            for (int t = 0; t < 4; ++t)
                G[(size_t)row * WSTRIDE + c0 + t * 16 + llo] = __float2half_rn(acc0[t][i] * dv);
        }
        int row1 = rbase + 16 + i;
        if (row1 < N) {
            float dv = dinv[row1];
#pragma unroll
            for (int t = 0; t < 4; ++t)
                G[(size_t)row1 * WSTRIDE + c0 + t * 16 + llo] = __float2half_rn(acc1[t][i] * dv);
        }
    }
}

// ---------------- Aggregate F=128, COLUMN-SPLIT; outputs pre-split bf16 hi/lo h ----------------
// Half-wave (32 lanes x half2 = 128B = one L2 line) per node per pass.
// Out = relu(dinv*(sum G[j] + G[self]) + b) written as h_hi/h_lo bf16 planes
// (feeds next GEMM's A-fragments directly -> no conversion in GEMM).

__global__ __launch_bounds__(256) void aggregate128_kernel(const __half* __restrict__ G,
                                                           const float* __restrict__ dinv,
                                                           const int* __restrict__ row_ptr,
                                                           const int* __restrict__ col,
                                                           const float* __restrict__ bias,
                                                           ushort* __restrict__ Hh,
                                                           ushort* __restrict__ Hl, int N) {
    int node = blockIdx.x * 8 + (threadIdx.x >> 5);
    int ln = threadIdx.x & 31;
    if (node >= N) return;
    int beg = row_ptr[node];
    int end = row_ptr[node + 1];
    int cb = blockIdx.y * 32;  // half2 column offset of this half

    const __half2* Gp = reinterpret_cast<const __half2*>(G) + cb;
    float2 a[8];
    a[0] = __half22float2(Gp[(size_t)node * 64 + ln]);  // self
#pragma unroll
    for (int i = 1; i < 8; ++i) a[i] = make_float2(0.f, 0.f);

    for (int e = beg; e < end; e += 8) {
        int last = end - 1;
        int jx[8];
#pragma unroll
        for (int i = 0; i < 8; ++i) jx[i] = col[min(e + i, last)];
        float2 v[8];
#pragma unroll
        for (int i = 0; i < 8; ++i) v[i] = __half22float2(Gp[(size_t)jx[i] * 64 + ln]);
        a[0].x += v[0].x; a[0].y += v[0].y;
#pragma unroll
        for (int i = 1; i < 8; ++i)
            if (e + i < end) { a[i].x += v[i].x; a[i].y += v[i].y; }
    }
#pragma unroll
    for (int i = 1; i < 8; ++i) { a[0].x += a[i].x; a[0].y += a[i].y; }

    float s = dinv[node];
    float2 bb = reinterpret_cast<const float2*>(bias)[cb + ln];
    float ox = fmaxf(fmaf(s, a[0].x, bb.x), 0.f);
    float oy = fmaxf(fmaf(s, a[0].y, bb.y), 0.f);

    ushort hx = f2bf_rne(ox);
    ushort lx = f2bf_rne(ox - bf2f(hx));
    ushort hy = f2bf_rne(oy);
    ushort ly = f2bf_rne(oy - bf2f(hy));
    size_t o = (size_t)node * 128 + (size_t)(cb + ln) * 2;
    *reinterpret_cast<uint*>(&Hh[o]) = (uint)hx | ((uint)hy << 16);
    *reinterpret_cast<uint*>(&Hl[o]) = (uint)lx | ((uint)ly << 16);
}

// ---------------- Aggregate F=64: 2 nodes/wave (32 lanes x half2), 8-deep; fp32 out ----------------

__global__ __launch_bounds__(256) void aggregate64_kernel(const __half* __restrict__ G,
                                                          const float* __restrict__ dinv,
                                                          const int* __restrict__ row_ptr,
                                                          const int* __restrict__ col,
                                                          const float* __restrict__ bias,
                                                          float* __restrict__ Out, int N) {
    int node = blockIdx.x * 8 + (threadIdx.x >> 5);
    int ln = threadIdx.x & 31;
    if (node >= N) return;
    int beg = row_ptr[node];
    int end = row_ptr[node + 1];

    const __half2* Gp = reinterpret_cast<const __half2*>(G);
    float2 a[8];
    a[0] = __half22float2(Gp[(size_t)node * 32 + ln]);  // self
#pragma unroll
    for (int i = 1; i < 8; ++i) a[i] = make_float2(0.f, 0.f);

    for (int e = beg; e < end; e += 8) {
        int last = end - 1;
        int jx[8];
#pragma unroll
        for (int i = 0; i < 8; ++i) jx[i] = col[min(e + i, last)];
        float2 v[8];
#pragma unroll
        for (int i = 0; i < 8; ++i) v[i] = __half22float2(Gp[(size_t)jx[i] * 32 + ln]);
        a[0].x += v[0].x; a[0].y += v[0].y;
#pragma unroll
        for (int i = 1; i < 8; ++i)
            if (e + i < end) { a[i].x += v[i].x; a[i].y += v[i].y; }
    }
#pragma unroll
    for (int i = 1; i < 8; ++i) { a[0].x += a[i].x; a[0].y += a[i].y; }

    float s = dinv[node];
    float2 bb = reinterpret_cast<const float2*>(bias)[ln];
    float2 o;
    o.x = fmaf(s, a[0].x, bb.x);
    o.y = fmaf(s, a[0].y, bb.y);
    reinterpret_cast<float2*>(Out)[(size_t)node * 32 + ln] = o;
}

// ---------------- launch ----------------

extern "C" void kernel_launch(void* const* d_in, const int* in_sizes, int n_in,
                              void* d_out, int out_size, void* d_ws, size_t ws_size,
                              hipStream_t stream) {
    const float* x  = (const float*)d_in[0];
    const int*  edge = (const int*)d_in[1];
    const float* W1 = (const float*)d_in[2];
    const float* b1 = (const float*)d_in[3];
    const float* W2 = (const float*)d_in[4];
    const float* b2 = (const float*)d_in[5];
    const float* W3 = (const float*)d_in[6];
    const float* b3 = (const float*)d_in[7];
    float* out = (float*)d_out;

    const int N = NN, E = NE;
    const int* src = edge;
    const int* dst = edge + E;
    const int NBLK = (N + 1023) / 1024;  // 49

    size_t off = 0;
    auto alloc = [&](size_t bytes) {
        void* p = (char*)d_ws + off;
        off = (off + bytes + 255) & ~(size_t)255;
        return p;
    };
    int*    cnt      = (int*)alloc((size_t)N * 4);
    int*    row_ptr  = (int*)alloc((size_t)(N + 1) * 4);
    int*    tmp_ptr  = (int*)alloc((size_t)N * 4);
    int*    colv     = (int*)alloc((size_t)E * 4);
    float*  dinv     = (float*)alloc((size_t)N * 4);
    int*    blk_sums = (int*)alloc((size_t)NBLK * 4);
    __half* g        = (__half*)alloc((size_t)N * 128 * 2);
    ushort* xh       = (ushort*)alloc((size_t)N * 128 * 2);
    ushort* xl       = (ushort*)alloc((size_t)N * 128 * 2);
    ushort* hh       = (ushort*)alloc((size_t)N * 128 * 2);
    ushort* hl       = (ushort*)alloc((size_t)N * 128 * 2);
    (void)ws_size; (void)in_sizes; (void)n_in; (void)out_size;

    hipMemsetAsync(cnt, 0, (size_t)N * 4, stream);
    count_kernel<<<(E + 255) / 256, 256, 0, stream>>>(dst, cnt, E);
    block_reduce_kernel<<<NBLK, 256, 0, stream>>>(cnt, blk_sums, N);
    scan_sums_kernel<<<1, 64, 0, stream>>>(blk_sums, NBLK);
    block_scan_kernel<<<NBLK, 256, 0, stream>>>(cnt, blk_sums, row_ptr, tmp_ptr, dinv, N, E);
    fill_kernel<<<(E + 255) / 256, 256, 0, stream>>>(src, dst, tmp_ptr, colv, E);
    split_x_kernel<<<(N * 128 / 8 + 255) / 256, 256, 0, stream>>>(x, xh, xl, N * 128 / 8);

    dim3 gemm128_grid((N + 127) / 128, 2);
    dim3 gemm64_grid((N + 127) / 128, 1);
    dim3 agg128_grid((N + 7) / 8, 2);  // y = column half
    dim3 agg64_grid((N + 7) / 8);

    gemm_mfma_kernel<128><<<gemm128_grid, 256, 0, stream>>>(xh, xl, W1, dinv, g, N);
    aggregate128_kernel<<<agg128_grid, 256, 0, stream>>>(g, dinv, row_ptr, colv, b1, hh, hl, N);

    gemm_mfma_kernel<128><<<gemm128_grid, 256, 0, stream>>>(hh, hl, W2, dinv, g, N);
    aggregate128_kernel<<<agg128_grid, 256, 0, stream>>>(g, dinv, row_ptr, colv, b2, hh, hl, N);

    gemm_mfma_kernel<64><<<gemm64_grid, 256, 0, stream>>>(hh, hl, W3, dinv, g, N);
    aggregate64_kernel<<<agg64_grid, 256, 0, stream>>>(g, dinv, row_ptr, colv, b3, out, N);
}

// Round 15
// 286.796 us; speedup vs baseline: 1.0438x; 1.0438x over previous
//
#include <hip/hip_runtime.h>
#include <hip/hip_fp16.h>
#include <math.h>

#define NN 50000
#define NE 640000

typedef __bf16 bf16x8 __attribute__((ext_vector_type(8)));
typedef float f32x4 __attribute__((ext_vector_type(4)));

__device__ inline ushort f2bf_rne(float f) {
    uint u = __float_as_uint(f);
    uint r = u + 0x7FFFu + ((u >> 16) & 1u);
    return (ushort)(r >> 16);
}
__device__ inline float bf2f(ushort h) { return __uint_as_float(((uint)h) << 16); }

union BfU {
    ushort u[8];
    uint4 q;
    bf16x8 v;
};
union HU {
    uint4 q;
    __half h[8];
};

__device__ inline void split8(const float f[8], bf16x8& hi, bf16x8& lo) {
    BfU H, L;
#pragma unroll
    for (int i = 0; i < 8; ++i) {
        ushort h = f2bf_rne(f[i]);
        H.u[i] = h;
        L.u[i] = f2bf_rne(f[i] - bf2f(h));
    }
    hi = H.v;
    lo = L.v;
}

template <typename TIN>
__device__ inline void load8f(const TIN* p, float f[8]);

template <>
__device__ inline void load8f<float>(const float* p, float f[8]) {
    float4 a = *reinterpret_cast<const float4*>(p);
    float4 b = *reinterpret_cast<const float4*>(p + 4);
    f[0] = a.x; f[1] = a.y; f[2] = a.z; f[3] = a.w;
    f[4] = b.x; f[5] = b.y; f[6] = b.z; f[7] = b.w;
}

template <>
__device__ inline void load8f<__half>(const __half* p, float f[8]) {
    HU u;
    u.q = *reinterpret_cast<const uint4*>(p);
#pragma unroll
    for (int i = 0; i < 8; ++i) f[i] = __half2float(u.h[i]);
}

// ---------------- CSR build ----------------

__global__ void count_kernel(const int* __restrict__ dst, int* __restrict__ cnt, int E) {
    int e = blockIdx.x * blockDim.x + threadIdx.x;
    if (e < E) atomicAdd(&cnt[dst[e]], 1);
}

__global__ __launch_bounds__(256) void block_reduce_kernel(const int* __restrict__ cnt,
                                                           int* __restrict__ blk_sums, int N) {
    __shared__ int red[256];
    int tid = threadIdx.x;
    int base = blockIdx.x * 1024 + tid * 4;
    int s = 0;
    if (base + 3 < N) {
        int4 v = *reinterpret_cast<const int4*>(&cnt[base]);
        s = v.x + v.y + v.z + v.w;
    } else {
        for (int i = 0; i < 4; ++i)
            if (base + i < N) s += cnt[base + i];
    }
    red[tid] = s;
    __syncthreads();
    for (int off = 128; off > 0; off >>= 1) {
        if (tid < off) red[tid] += red[tid + off];
        __syncthreads();
    }
    if (tid == 0) blk_sums[blockIdx.x] = red[0];
}

__global__ __launch_bounds__(64) void scan_sums_kernel(int* __restrict__ blk_sums, int nblk) {
    int lane = threadIdx.x;
    int v = (lane < nblk) ? blk_sums[lane] : 0;
    for (int off = 1; off < 64; off <<= 1) {
        int u = __shfl_up(v, off);
        if (lane >= off) v += u;
    }
    int ex = __shfl_up(v, 1);
    if (lane == 0) ex = 0;
    if (lane < nblk) blk_sums[lane] = ex;
}

__global__ __launch_bounds__(256) void block_scan_kernel(const int* __restrict__ cnt,
                                                         const int* __restrict__ blk_offs,
                                                         int* __restrict__ row_ptr,
                                                         int* __restrict__ tmp_ptr,
                                                         float* __restrict__ dinv,
                                                         int N, int E) {
    __shared__ int warp_sums[4];
    int tid = threadIdx.x;
    int base = blockIdx.x * 1024 + tid * 4;
    int c[4];
    int s = 0;
#pragma unroll
    for (int i = 0; i < 4; ++i) {
        int idx = base + i;
        c[i] = (idx < N) ? cnt[idx] : 0;
        s += c[i];
    }
    int lane = tid & 63;
    int wv = tid >> 6;
    int v = s;
    for (int off = 1; off < 64; off <<= 1) {
        int u = __shfl_up(v, off);
        if (lane >= off) v += u;
    }
    if (lane == 63) warp_sums[wv] = v;
    __syncthreads();
    int woff = 0;
    for (int w = 0; w < wv; ++w) woff += warp_sums[w];
    int run = blk_offs[blockIdx.x] + woff + (v - s);
#pragma unroll
    for (int i = 0; i < 4; ++i) {
        int idx = base + i;
        if (idx < N) {
            row_ptr[idx] = run;
            tmp_ptr[idx] = run;
            run += c[i];
            dinv[idx] = rsqrtf((float)c[i] + 1.0f);
        }
    }
    if (blockIdx.x == 0 && tid == 0) row_ptr[N] = E;
}

__global__ void fill_kernel(const int* __restrict__ src, const int* __restrict__ dst,
                            int* __restrict__ tmp_ptr, int* __restrict__ col, int E) {
    int e = blockIdx.x * blockDim.x + threadIdx.x;
    if (e < E) {
        int d = dst[e];
        int pos = atomicAdd(&tmp_ptr[d], 1);
        col[pos] = src[e];
    }
}

// ---------------- GEMM via split-bf16 MFMA, fp16 output, TIN input ----------------
// G[r][c] = fp16( dinv[r] * sum_k X[r][k] * W[k][c] ), K = 128.
// x = hi + lo (bf16 each); x*w ~= hi*hi + lo*hi + hi*lo (lo*lo dropped).
// 256 thr = 4 waves; 128 rows x 64 cols per block (blockIdx.y = col half).
// W converted once into LDS as MFMA-tiled bf16 hi/lo (float4-vectorized staging).
// mfma_f32_16x16x32_bf16; D layout: col = lane&15, row = (lane>>4)*4 + reg (m89).

template <int WSTRIDE, typename TIN>
__global__ __launch_bounds__(256, 3) void gemm_mfma_kernel(const TIN* __restrict__ X,
                                                           const float* __restrict__ W,
                                                           const float* __restrict__ dinv,
                                                           __half* __restrict__ G, int N) {
    __shared__ ushort lds_hi[16 * 512];
    __shared__ ushort lds_lo[16 * 512];
    const int tid = threadIdx.x;
    const int c0 = blockIdx.y * 64;

    // ---- stage W: float4 global reads (8 iters/thread instead of 32) ----
    for (int idx4 = tid; idx4 < 128 * 16; idx4 += 256) {
        int k = idx4 >> 4;
        int n4 = (idx4 & 15) << 2;
        float4 w4 = *reinterpret_cast<const float4*>(&W[k * WSTRIDE + c0 + n4]);
        float wf[4] = {w4.x, w4.y, w4.z, w4.w};
        int kt = k >> 5;
        int koff = ((k >> 3) & 3) << 4;
        int kin = k & 7;
#pragma unroll
        for (int j = 0; j < 4; ++j) {
            int n = n4 + j;
            ushort h = f2bf_rne(wf[j]);
            ushort l = f2bf_rne(wf[j] - bf2f(h));
            int t = n >> 4;
            int ln = (n & 15) | koff;
            int pos = (kt * 4 + t) * 512 + ln * 8 + kin;
            lds_hi[pos] = h;
            lds_lo[pos] = l;
        }
    }
    __syncthreads();

    const int wave = tid >> 6;
    const int lane = tid & 63;
    const int lhi = lane >> 4;
    const int llo = lane & 15;
    const int r0 = blockIdx.x * 128 + wave * 32;

    int ar0 = min(r0 + llo, N - 1);
    int ar1 = min(r0 + 16 + llo, N - 1);
    const TIN* Xr0 = X + (size_t)ar0 * 128 + lhi * 8;
    const TIN* Xr1 = X + (size_t)ar1 * 128 + lhi * 8;

    f32x4 acc0[4], acc1[4];
#pragma unroll
    for (int t = 0; t < 4; ++t) {
        acc0[t] = (f32x4){0.f, 0.f, 0.f, 0.f};
        acc1[t] = (f32x4){0.f, 0.f, 0.f, 0.f};
    }

#pragma unroll
    for (int kt = 0; kt < 4; ++kt) {
        const ushort* hp = &lds_hi[kt * 4 * 512 + lane * 8];
        const ushort* lp = &lds_lo[kt * 4 * 512 + lane * 8];
        bf16x8 bh[4], bl[4];
#pragma unroll
        for (int t = 0; t < 4; ++t) {
            bh[t] = *reinterpret_cast<const bf16x8*>(hp + t * 512);
            bl[t] = *reinterpret_cast<const bf16x8*>(lp + t * 512);
        }
        float f0[8], f1[8];
        load8f<TIN>(Xr0 + kt * 32, f0);
        load8f<TIN>(Xr1 + kt * 32, f1);
        bf16x8 ah0, al0, ah1, al1;
        split8(f0, ah0, al0);
        split8(f1, ah1, al1);
#pragma unroll
        for (int t = 0; t < 4; ++t) {
            acc0[t] = __builtin_amdgcn_mfma_f32_16x16x32_bf16(ah0, bh[t], acc0[t], 0, 0, 0);
            acc1[t] = __builtin_amdgcn_mfma_f32_16x16x32_bf16(ah1, bh[t], acc1[t], 0, 0, 0);
            acc0[t] = __builtin_amdgcn_mfma_f32_16x16x32_bf16(al0, bh[t], acc0[t], 0, 0, 0);
            acc1[t] = __builtin_amdgcn_mfma_f32_16x16x32_bf16(al1, bh[t], acc1[t], 0, 0, 0);
            acc0[t] = __builtin_amdgcn_mfma_f32_16x16x32_bf16(ah0, bl[t], acc0[t], 0, 0, 0);
            acc1[t] = __builtin_amdgcn_mfma_f32_16x16x32_bf16(ah1, bl[t], acc1[t], 0, 0, 0);
        }
    }

    const int rbase = r0 + lhi * 4;
#pragma unroll
    for (int i = 0; i < 4; ++i) {
        int row = rbase + i;
        if (row < N) {
            float dv = dinv[row];
#pragma unroll
            for (int t = 0; t < 4; ++t)
                G[(size_t)row * WSTRIDE + c0 + t * 16 + llo] = __float2half_rn(acc0[t][i] * dv);
        }
        int row1 = rbase + 16 + i;
        if (row1 < N) {
            float dv = dinv[row1];
#pragma unroll
            for (int t = 0; t < 4; ++t)
                G[(size_t)row1 * WSTRIDE + c0 + t * 16 + llo] = __float2half_rn(acc1[t][i] * dv);
        }
    }
}

// ---------------- Aggregate F=128, COLUMN-SPLIT: blockIdx.y = col half (64 cols) ----------------
// Half-wave (32 lanes x half2 = 128B = one L2 line) per node per pass.
// Working set per pass = 6.4 MB -> better per-XCD L2 hit rate; every fetched
// 128B line fully used (verified -8us in R12).

__global__ __launch_bounds__(256) void aggregate128_kernel(const __half* __restrict__ G,
                                                           const float* __restrict__ dinv,
                                                           const int* __restrict__ row_ptr,
                                                           const int* __restrict__ col,
                                                           const float* __restrict__ bias,
                                                           __half* __restrict__ Out, int N) {
    int node = blockIdx.x * 8 + (threadIdx.x >> 5);
    int ln = threadIdx.x & 31;
    if (node >= N) return;
    int beg = row_ptr[node];
    int end = row_ptr[node + 1];
    int cb = blockIdx.y * 32;  // half2 offset of this column half

    const __half2* Gp = reinterpret_cast<const __half2*>(G) + cb;
    float2 a[8];
    a[0] = __half22float2(Gp[(size_t)node * 64 + ln]);  // self
#pragma unroll
    for (int i = 1; i < 8; ++i) a[i] = make_float2(0.f, 0.f);

    for (int e = beg; e < end; e += 8) {
        int last = end - 1;
        int jx[8];
#pragma unroll
        for (int i = 0; i < 8; ++i) jx[i] = col[min(e + i, last)];
        float2 v[8];
#pragma unroll
        for (int i = 0; i < 8; ++i) v[i] = __half22float2(Gp[(size_t)jx[i] * 64 + ln]);
        a[0].x += v[0].x; a[0].y += v[0].y;
#pragma unroll
        for (int i = 1; i < 8; ++i)
            if (e + i < end) { a[i].x += v[i].x; a[i].y += v[i].y; }
    }
#pragma unroll
    for (int i = 1; i < 8; ++i) { a[0].x += a[i].x; a[0].y += a[i].y; }

    float s = dinv[node];
    float2 bb = reinterpret_cast<const float2*>(bias)[cb + ln];
    float ox = fmaxf(fmaf(s, a[0].x, bb.x), 0.f);
    float oy = fmaxf(fmaf(s, a[0].y, bb.y), 0.f);
    reinterpret_cast<__half2*>(Out)[(size_t)node * 64 + cb + ln] =
        __float22half2_rn(make_float2(ox, oy));
}

// ---------------- Aggregate F=64: 2 nodes/wave (32 lanes x half2), 8-deep; fp32 out ----------------

__global__ __launch_bounds__(256) void aggregate64_kernel(const __half* __restrict__ G,
                                                          const float* __restrict__ dinv,
                                                          const int* __restrict__ row_ptr,
                                                          const int* __restrict__ col,
                                                          const float* __restrict__ bias,
                                                          float* __restrict__ Out, int N) {
    int node = blockIdx.x * 8 + (threadIdx.x >> 5);
    int ln = threadIdx.x & 31;
    if (node >= N) return;
    int beg = row_ptr[node];
    int end = row_ptr[node + 1];

    const __half2* Gp = reinterpret_cast<const __half2*>(G);
    float2 a[8];
    a[0] = __half22float2(Gp[(size_t)node * 32 + ln]);  // self
#pragma unroll
    for (int i = 1; i < 8; ++i) a[i] = make_float2(0.f, 0.f);

    for (int e = beg; e < end; e += 8) {
        int last = end - 1;
        int jx[8];
#pragma unroll
        for (int i = 0; i < 8; ++i) jx[i] = col[min(e + i, last)];
        float2 v[8];
#pragma unroll
        for (int i = 0; i < 8; ++i) v[i] = __half22float2(Gp[(size_t)jx[i] * 32 + ln]);
        a[0].x += v[0].x; a[0].y += v[0].y;
#pragma unroll
        for (int i = 1; i < 8; ++i)
            if (e + i < end) { a[i].x += v[i].x; a[i].y += v[i].y; }
    }
#pragma unroll
    for (int i = 1; i < 8; ++i) { a[0].x += a[i].x; a[0].y += a[i].y; }

    float s = dinv[node];
    float2 bb = reinterpret_cast<const float2*>(bias)[ln];
    float2 o;
    o.x = fmaf(s, a[0].x, bb.x);
    o.y = fmaf(s, a[0].y, bb.y);
    reinterpret_cast<float2*>(Out)[(size_t)node * 32 + ln] = o;
}

// ---------------- launch ----------------

extern "C" void kernel_launch(void* const* d_in, const int* in_sizes, int n_in,
                              void* d_out, int out_size, void* d_ws, size_t ws_size,
                              hipStream_t stream) {
    const float* x  = (const float*)d_in[0];
    const int*  edge = (const int*)d_in[1];
    const float* W1 = (const float*)d_in[2];
    const float* b1 = (const float*)d_in[3];
    const float* W2 = (const float*)d_in[4];
    const float* b2 = (const float*)d_in[5];
    const float* W3 = (const float*)d_in[6];
    const float* b3 = (const float*)d_in[7];
    float* out = (float*)d_out;

    const int N = NN, E = NE;
    const int* src = edge;
    const int* dst = edge + E;
    const int NBLK = (N + 1023) / 1024;  // 49

    size_t off = 0;
    auto alloc = [&](size_t bytes) {
        void* p = (char*)d_ws + off;
        off = (off + bytes + 255) & ~(size_t)255;
        return p;
    };
    int*    cnt      = (int*)alloc((size_t)N * 4);
    int*    row_ptr  = (int*)alloc((size_t)(N + 1) * 4);
    int*    tmp_ptr  = (int*)alloc((size_t)N * 4);
    int*    colv     = (int*)alloc((size_t)E * 4);
    float*  dinv     = (float*)alloc((size_t)N * 4);
    int*    blk_sums = (int*)alloc((size_t)NBLK * 4);
    __half* g        = (__half*)alloc((size_t)N * 128 * 2);
    __half* h        = (__half*)alloc((size_t)N * 128 * 2);
    (void)ws_size; (void)in_sizes; (void)n_in; (void)out_size;

    hipMemsetAsync(cnt, 0, (size_t)N * 4, stream);
    count_kernel<<<(E + 255) / 256, 256, 0, stream>>>(dst, cnt, E);
    block_reduce_kernel<<<NBLK, 256, 0, stream>>>(cnt, blk_sums, N);
    scan_sums_kernel<<<1, 64, 0, stream>>>(blk_sums, NBLK);
    block_scan_kernel<<<NBLK, 256, 0, stream>>>(cnt, blk_sums, row_ptr, tmp_ptr, dinv, N, E);
    fill_kernel<<<(E + 255) / 256, 256, 0, stream>>>(src, dst, tmp_ptr, colv, E);

    dim3 gemm128_grid((N + 127) / 128, 2);
    dim3 gemm64_grid((N + 127) / 128, 1);
    dim3 agg128_grid((N + 7) / 8, 2);  // y = column half
    dim3 agg64_grid((N + 7) / 8);

    gemm_mfma_kernel<128, float><<<gemm128_grid, 256, 0, stream>>>(x, W1, dinv, g, N);
    aggregate128_kernel<<<agg128_grid, 256, 0, stream>>>(g, dinv, row_ptr, colv, b1, h, N);

    gemm_mfma_kernel<128, __half><<<gemm128_grid, 256, 0, stream>>>(h, W2, dinv, g, N);
    aggregate128_kernel<<<agg128_grid, 256, 0, stream>>>(g, dinv, row_ptr, colv, b2, h, N);

    gemm_mfma_kernel<64, __half><<<gemm64_grid, 256, 0, stream>>>(h, W3, dinv, g, N);
    aggregate64_kernel<<<agg64_grid, 256, 0, stream>>>(g, dinv, row_ptr, colv, b3, out, N);
}